// Round 2
// baseline (314.947 us; speedup 1.0000x reference)
//
#include <hip/hip_runtime.h>
#include <hip/hip_bf16.h>

// ---------------------------------------------------------------------------
// AttentionBlock: B=8, L=1024, C=1024, H=8, ch=128.
// I/O is fp32 (per reference); internal compute bf16 MFMA with fp32 accum.
//   xn = LayerNorm(x)*g + b                      (fp32 in, bf16 out)
//   qkv = xn @ w_qkv + b_qkv ; q,k scaled by 128^-0.25   (bf16 MFMA)
//   heads: free flat reinterpret [B,L,C] -> [B*H, L, ch]
//   S = QK^T per head, softmax (no max-sub: logits are small), O = P V
//   out = attn @ w_out + b_out + xn              (fp32 out)
// ---------------------------------------------------------------------------

typedef __attribute__((ext_vector_type(8))) short short8;
typedef __attribute__((ext_vector_type(4))) float f32x4;

#define QK_SCALE 0.29730177875068026f  // 128^-0.25

__device__ __forceinline__ float bf2f(ushort u) {
    union { float f; unsigned int i; } c; c.i = ((unsigned int)u) << 16; return c.f;
}
__device__ __forceinline__ ushort f2bf(float f) {
    union { float f; unsigned int i; } c; c.f = f;
    unsigned int x = c.i;
    return (ushort)((x + 0x7FFFu + ((x >> 16) & 1u)) >> 16);  // RNE
}

// ---------------------------------------------------------------------------
// LayerNorm: one block per row of 1024.  4 elems/thread.  fp32 in -> bf16 out.
// ---------------------------------------------------------------------------
__global__ __launch_bounds__(256) void ln_kernel(
    const float* __restrict__ x, const float* __restrict__ g,
    const float* __restrict__ b, ushort* __restrict__ xn) {
    int row = blockIdx.x;
    int tid = threadIdx.x;
    const float* xr = x + (size_t)row * 1024;
    float4 v4 = *(const float4*)(xr + tid * 4);
    float v[4] = {v4.x, v4.y, v4.z, v4.w};
    float s1 = 0.f, s2 = 0.f;
#pragma unroll
    for (int j = 0; j < 4; j++) { s1 += v[j]; s2 += v[j] * v[j]; }
#pragma unroll
    for (int m = 32; m >= 1; m >>= 1) { s1 += __shfl_xor(s1, m); s2 += __shfl_xor(s2, m); }
    __shared__ float r1[4], r2[4];
    int lane = tid & 63, w = tid >> 6;
    if (lane == 0) { r1[w] = s1; r2[w] = s2; }
    __syncthreads();
    s1 = r1[0] + r1[1] + r1[2] + r1[3];
    s2 = r2[0] + r2[1] + r2[2] + r2[3];
    float mu = s1 * (1.0f / 1024.0f);
    float var = s2 * (1.0f / 1024.0f) - mu * mu;
    float rs = rsqrtf(var + 1e-5f);
    int c0 = tid * 4;
    float4 gg = *(const float4*)(g + c0);
    float4 bb = *(const float4*)(b + c0);
    float gA[4] = {gg.x, gg.y, gg.z, gg.w};
    float bA[4] = {bb.x, bb.y, bb.z, bb.w};
    ushort o[4];
#pragma unroll
    for (int j = 0; j < 4; j++) {
        float y = (v[j] - mu) * rs * gA[j] + bA[j];
        o[j] = f2bf(y);
    }
    uint2 pk;
    pk.x = (uint)o[0] | ((uint)o[1] << 16);
    pk.y = (uint)o[2] | ((uint)o[3] << 16);
    *(uint2*)(xn + (size_t)row * 1024 + c0) = pk;
}

// ---------------------------------------------------------------------------
// Tiled 32x32 transpose + fp32->bf16 convert: in[R][Cc] fp32 -> out[Cc][R] bf16
// ---------------------------------------------------------------------------
__global__ __launch_bounds__(256) void transpose_kernel(
    const float* __restrict__ in, ushort* __restrict__ out, int R, int Cc) {
    __shared__ ushort t[32][33];
    int bx = blockIdx.x * 32, by = blockIdx.y * 32;
    int tx = threadIdx.x & 31, ty = threadIdx.x >> 5;  // ty in [0,8)
#pragma unroll
    for (int j = 0; j < 32; j += 8)
        t[ty + j][tx] = f2bf(in[(size_t)(by + ty + j) * Cc + bx + tx]);
    __syncthreads();
#pragma unroll
    for (int j = 0; j < 32; j += 8)
        out[(size_t)(bx + ty + j) * R + by + tx] = t[tx][ty + j];
}

// ---------------------------------------------------------------------------
// GEMM: C[M,N] = A[M,1024] @ Bt[N,1024]^T   (K fixed = 1024), A/Bt bf16.
// 128x128 block tile, BK=32, 4 waves in 2x2, each wave 64x64 via 4x4 MFMAs.
// MODE 0: +bias(fp32), scale cols<2048 by QK_SCALE, split-write bf16 q/k/v.
// MODE 1: +bias(fp32) +residual(xn bf16), write fp32 to outf.
// ---------------------------------------------------------------------------
template <int MODE>
__global__ __launch_bounds__(256) void gemm_bt(
    const ushort* __restrict__ A, const ushort* __restrict__ Bt,
    const float* __restrict__ bias, ushort* __restrict__ out0,
    ushort* __restrict__ out1, ushort* __restrict__ out2,
    const ushort* __restrict__ resid, float* __restrict__ outf) {
    const int K = 1024;
    __shared__ __align__(16) ushort As[128 * 32];
    __shared__ __align__(16) ushort Bs[128 * 32];

    int tid = threadIdx.x;
    int lane = tid & 63, w = tid >> 6;
    int l15 = lane & 15, q4 = lane >> 4;
    int wr = (w >> 1) * 64, wc = (w & 1) * 64;
    int rowBase = blockIdx.y * 128, colBase = blockIdx.x * 128;

    f32x4 acc[4][4];
    f32x4 zero = {0.f, 0.f, 0.f, 0.f};
#pragma unroll
    for (int mi = 0; mi < 4; mi++)
#pragma unroll
        for (int ni = 0; ni < 4; ni++) acc[mi][ni] = zero;

    for (int kt = 0; kt < K / 32; kt++) {
        __syncthreads();
#pragma unroll
        for (int p = 0; p < 2; p++) {
            int i = tid + p * 256;
            int r = i >> 2, c8 = (i & 3) * 8;
            *(uint4*)&As[r * 32 + c8] =
                *(const uint4*)&A[(size_t)(rowBase + r) * K + kt * 32 + c8];
            *(uint4*)&Bs[r * 32 + c8] =
                *(const uint4*)&Bt[(size_t)(colBase + r) * K + kt * 32 + c8];
        }
        __syncthreads();

        short8 aF[4], bF[4];
#pragma unroll
        for (int mi = 0; mi < 4; mi++)
            aF[mi] = *(const short8*)&As[(wr + mi * 16 + l15) * 32 + q4 * 8];
#pragma unroll
        for (int ni = 0; ni < 4; ni++)
            bF[ni] = *(const short8*)&Bs[(wc + ni * 16 + l15) * 32 + q4 * 8];
#pragma unroll
        for (int mi = 0; mi < 4; mi++)
#pragma unroll
            for (int ni = 0; ni < 4; ni++)
                acc[mi][ni] = __builtin_amdgcn_mfma_f32_16x16x32_bf16(
                    aF[mi], bF[ni], acc[mi][ni], 0, 0, 0);
    }

    // Epilogue.  C layout: col = lane&15, row = (lane>>4)*4 + r  [m89/m91]
#pragma unroll
    for (int mi = 0; mi < 4; mi++)
#pragma unroll
        for (int ni = 0; ni < 4; ni++) {
            f32x4 a = acc[mi][ni];
            int col = colBase + wc + ni * 16 + l15;
            float bv = bias[col];
#pragma unroll
            for (int r = 0; r < 4; r++) {
                int row = rowBase + wr + mi * 16 + q4 * 4 + r;
                float val = a[r] + bv;
                if (MODE == 0) {
                    if (col < 2048) val *= QK_SCALE;
                    int bsel = col >> 10, cc = col & 1023;
                    ushort* dst = (bsel == 0) ? out0 : ((bsel == 1) ? out1 : out2);
                    dst[(size_t)row * 1024 + cc] = f2bf(val);
                } else {
                    val += bf2f(resid[(size_t)row * 1024 + col]);
                    outf[(size_t)row * 1024 + col] = val;
                }
            }
        }
}

// ---------------------------------------------------------------------------
// Attention: one block = (head g, 64 q-rows).  K/V tiles of 64 keys.
// No max-subtraction softmax (logits small): O = (sum exp(S) V) / sum exp(S)
// 4 waves; each wave owns 16 q-rows.
// LDS strides padded to break the 256B row-stride bank pathology.
// ---------------------------------------------------------------------------
__global__ __launch_bounds__(256) void attn_kernel(
    const ushort* __restrict__ qb, const ushort* __restrict__ kb,
    const ushort* __restrict__ vb, ushort* __restrict__ attnb) {
    const int HD = 128;      // head dim
    const int LH = 131072;   // per-head elems = 1024*128
    int g = blockIdx.x >> 4;     // head 0..63
    int qblk = blockIdx.x & 15;  // q block of 64 rows

    const ushort* Q = qb + (size_t)g * LH + qblk * 64 * HD;
    const ushort* Kp = kb + (size_t)g * LH;
    const ushort* Vp = vb + (size_t)g * LH;

    __shared__ __align__(16) ushort Qs[64 * 136];
    __shared__ __align__(16) ushort Ks[64 * 136];
    __shared__ __align__(16) ushort Vt[128 * 72];
    __shared__ __align__(16) ushort Ps[64 * 72];  // 4 waves x 16 rows

    int tid = threadIdx.x;
    int lane = tid & 63, w = tid >> 6;
    int l15 = lane & 15, q4 = lane >> 4;

    // Stage Q (64x128)
#pragma unroll
    for (int p = 0; p < 4; p++) {
        int i = tid + p * 256;
        int r = i >> 4, c8 = (i & 15) * 8;
        *(uint4*)&Qs[r * 136 + c8] = *(const uint4*)&Q[r * HD + c8];
    }

    f32x4 o[8];
    f32x4 zero = {0.f, 0.f, 0.f, 0.f};
#pragma unroll
    for (int ni = 0; ni < 8; ni++) o[ni] = zero;
    float lsum[4] = {0.f, 0.f, 0.f, 0.f};

    for (int kt = 0; kt < 16; kt++) {
        __syncthreads();  // previous iter's reads done before overwrite
#pragma unroll
        for (int p = 0; p < 4; p++) {
            int i = tid + p * 256;
            int r = i >> 4, c8 = (i & 15) * 8;
            *(uint4*)&Ks[r * 136 + c8] = *(const uint4*)&Kp[(kt * 64 + r) * HD + c8];
            // V transposed: Vt[d][key]
            int key = i & 63, d0 = (i >> 6) * 8;
            uint4 vv = *(const uint4*)&Vp[(kt * 64 + key) * HD + d0];
            uint vw[4] = {vv.x, vv.y, vv.z, vv.w};
#pragma unroll
            for (int j = 0; j < 4; j++) {
                Vt[(d0 + 2 * j) * 72 + key] = (ushort)(vw[j] & 0xffff);
                Vt[(d0 + 2 * j + 1) * 72 + key] = (ushort)(vw[j] >> 16);
            }
        }
        __syncthreads();

        // S tile [16 q x 64 keys] per wave
        f32x4 sacc[4];
#pragma unroll
        for (int ni = 0; ni < 4; ni++) sacc[ni] = zero;
#pragma unroll
        for (int ks = 0; ks < 128; ks += 32) {
            short8 aF = *(const short8*)&Qs[(w * 16 + l15) * 136 + ks + q4 * 8];
#pragma unroll
            for (int ni = 0; ni < 4; ni++) {
                short8 bF = *(const short8*)&Ks[(ni * 16 + l15) * 136 + ks + q4 * 8];
                sacc[ni] = __builtin_amdgcn_mfma_f32_16x16x32_bf16(aF, bF, sacc[ni], 0, 0, 0);
            }
        }

        // P = exp(S); write to Ps (bf16), accumulate row sums
        float part[4] = {0.f, 0.f, 0.f, 0.f};
#pragma unroll
        for (int ni = 0; ni < 4; ni++) {
#pragma unroll
            for (int r = 0; r < 4; r++) {
                float pv = __expf(sacc[ni][r]);
                part[r] += pv;
                Ps[(w * 16 + q4 * 4 + r) * 72 + ni * 16 + l15] = f2bf(pv);
            }
        }
#pragma unroll
        for (int r = 0; r < 4; r++) {
#pragma unroll
            for (int m = 1; m < 16; m <<= 1) part[r] += __shfl_xor(part[r], m, 16);
            lsum[r] += part[r];
        }

        // O += P V   (A from Ps, B from Vt)
#pragma unroll
        for (int ks2 = 0; ks2 < 64; ks2 += 32) {
            short8 aF = *(const short8*)&Ps[(w * 16 + l15) * 72 + ks2 + q4 * 8];
#pragma unroll
            for (int ni = 0; ni < 8; ni++) {
                short8 bF = *(const short8*)&Vt[(ni * 16 + l15) * 72 + ks2 + q4 * 8];
                o[ni] = __builtin_amdgcn_mfma_f32_16x16x32_bf16(aF, bF, o[ni], 0, 0, 0);
            }
        }
    }

    float inv[4];
#pragma unroll
    for (int r = 0; r < 4; r++) inv[r] = 1.0f / lsum[r];
#pragma unroll
    for (int ni = 0; ni < 8; ni++) {
#pragma unroll
        for (int r = 0; r < 4; r++) {
            int qrow = qblk * 64 + w * 16 + q4 * 4 + r;
            attnb[(size_t)g * LH + qrow * HD + ni * 16 + l15] = f2bf(o[ni][r] * inv[r]);
        }
    }
}

// ---------------------------------------------------------------------------
extern "C" void kernel_launch(void* const* d_in, const int* in_sizes, int n_in,
                              void* d_out, int out_size, void* d_ws, size_t ws_size,
                              hipStream_t stream) {
    const float* x     = (const float*)d_in[0];
    const float* ln_g  = (const float*)d_in[1];
    const float* ln_b  = (const float*)d_in[2];
    const float* w_qkv = (const float*)d_in[3];
    const float* b_qkv = (const float*)d_in[4];
    const float* w_out = (const float*)d_in[5];
    const float* b_out = (const float*)d_in[6];
    float* out = (float*)d_out;

    const size_t MC = 8192ull * 1024ull;  // 8.39M elems
    ushort* xn    = (ushort*)d_ws;
    ushort* wqkvT = xn + MC;
    ushort* woutT = wqkvT + 3072ull * 1024ull;
    ushort* qbuf  = woutT + 1024ull * 1024ull;
    ushort* kbuf  = qbuf + MC;
    ushort* vbuf  = kbuf + MC;
    ushort* attnb = vbuf + MC;
    // total ws use: 46.14M ushorts ~= 92.3 MB

    ln_kernel<<<8192, 256, 0, stream>>>(x, ln_g, ln_b, xn);
    transpose_kernel<<<dim3(96, 32), 256, 0, stream>>>(w_qkv, wqkvT, 1024, 3072);
    transpose_kernel<<<dim3(32, 32), 256, 0, stream>>>(w_out, woutT, 1024, 1024);
    gemm_bt<0><<<dim3(24, 64), 256, 0, stream>>>(xn, wqkvT, b_qkv, qbuf, kbuf, vbuf, nullptr, nullptr);
    attn_kernel<<<1024, 256, 0, stream>>>(qbuf, kbuf, vbuf, attnb);
    gemm_bt<1><<<dim3(8, 64), 256, 0, stream>>>(attnb, woutT, b_out, nullptr, nullptr, nullptr, xn, out);
}

// Round 3
// 306.300 us; speedup vs baseline: 1.0282x; 1.0282x over previous
//
#include <hip/hip_runtime.h>
#include <hip/hip_bf16.h>

// ---------------------------------------------------------------------------
// AttentionBlock: B=8, L=1024, C=1024, H=8, ch=128.
// fp32 I/O, bf16 MFMA internal.  Faithful raw-reshape head split: head g's
// matrix = flat elements [g*131072, (g+1)*131072) of the [B,L,C] buffer,
// viewed as [1024][128]  (verified passing in round 2).
// ---------------------------------------------------------------------------

typedef __attribute__((ext_vector_type(8))) short short8;
typedef __attribute__((ext_vector_type(4))) float f32x4;

#define QK_SCALE 0.29730177875068026f  // 128^-0.25

__device__ __forceinline__ float bf2f(ushort u) {
    union { float f; unsigned int i; } c; c.i = ((unsigned int)u) << 16; return c.f;
}
__device__ __forceinline__ ushort f2bf(float f) {
    union { float f; unsigned int i; } c; c.f = f;
    unsigned int x = c.i;
    return (ushort)((x + 0x7FFFu + ((x >> 16) & 1u)) >> 16);  // RNE
}

// async 16B global->LDS (m97 pattern; LDS side must be base + lane*16)
__device__ __forceinline__ void gload_lds16(const ushort* g, ushort* l) {
    __builtin_amdgcn_global_load_lds(
        (const __attribute__((address_space(1))) unsigned int*)g,
        (__attribute__((address_space(3))) unsigned int*)l, 16, 0, 0);
}

// ---------------------------------------------------------------------------
// LayerNorm: one block per row of 1024.  fp32 in -> bf16 out.
// ---------------------------------------------------------------------------
__global__ __launch_bounds__(256) void ln_kernel(
    const float* __restrict__ x, const float* __restrict__ g,
    const float* __restrict__ b, ushort* __restrict__ xn) {
    int row = blockIdx.x;
    int tid = threadIdx.x;
    const float* xr = x + (size_t)row * 1024;
    float4 v4 = *(const float4*)(xr + tid * 4);
    float v[4] = {v4.x, v4.y, v4.z, v4.w};
    float s1 = 0.f, s2 = 0.f;
#pragma unroll
    for (int j = 0; j < 4; j++) { s1 += v[j]; s2 += v[j] * v[j]; }
#pragma unroll
    for (int m = 32; m >= 1; m >>= 1) { s1 += __shfl_xor(s1, m); s2 += __shfl_xor(s2, m); }
    __shared__ float r1[4], r2[4];
    int lane = tid & 63, w = tid >> 6;
    if (lane == 0) { r1[w] = s1; r2[w] = s2; }
    __syncthreads();
    s1 = r1[0] + r1[1] + r1[2] + r1[3];
    s2 = r2[0] + r2[1] + r2[2] + r2[3];
    float mu = s1 * (1.0f / 1024.0f);
    float var = s2 * (1.0f / 1024.0f) - mu * mu;
    float rs = rsqrtf(var + 1e-5f);
    int c0 = tid * 4;
    float4 gg = *(const float4*)(g + c0);
    float4 bb = *(const float4*)(b + c0);
    float gA[4] = {gg.x, gg.y, gg.z, gg.w};
    float bA[4] = {bb.x, bb.y, bb.z, bb.w};
    ushort o[4];
#pragma unroll
    for (int j = 0; j < 4; j++) o[j] = f2bf((v[j] - mu) * rs * gA[j] + bA[j]);
    uint2 pk;
    pk.x = (uint)o[0] | ((uint)o[1] << 16);
    pk.y = (uint)o[2] | ((uint)o[3] << 16);
    *(uint2*)(xn + (size_t)row * 1024 + c0) = pk;
}

// ---------------------------------------------------------------------------
// Weight transpose + fp32->bf16: in[R][Cc] fp32 -> out[Cc][R] bf16
// ---------------------------------------------------------------------------
__global__ __launch_bounds__(256) void transpose_kernel(
    const float* __restrict__ in, ushort* __restrict__ out, int R, int Cc) {
    __shared__ ushort t[32][33];
    int bx = blockIdx.x * 32, by = blockIdx.y * 32;
    int tx = threadIdx.x & 31, ty = threadIdx.x >> 5;
#pragma unroll
    for (int j = 0; j < 32; j += 8)
        t[ty + j][tx] = f2bf(in[(size_t)(by + ty + j) * Cc + bx + tx]);
    __syncthreads();
#pragma unroll
    for (int j = 0; j < 32; j += 8)
        out[(size_t)(bx + ty + j) * R + by + tx] = t[tx][ty + j];
}

// ---------------------------------------------------------------------------
// Per-head bf16 transpose: in [64][1024][128] -> out [64][128][1024]
// ---------------------------------------------------------------------------
__global__ __launch_bounds__(256) void transpose_head(
    const ushort* __restrict__ in, ushort* __restrict__ out) {
    __shared__ ushort t[32][33];
    int h = blockIdx.z;
    int j0 = blockIdx.y * 32;  // seq pos
    int d0 = blockIdx.x * 32;  // head dim
    int tx = threadIdx.x & 31, ty = threadIdx.x >> 5;
    const ushort* src = in + (size_t)h * 131072;
    ushort* dst = out + (size_t)h * 131072;
#pragma unroll
    for (int j = 0; j < 32; j += 8)
        t[ty + j][tx] = src[(size_t)(j0 + ty + j) * 128 + d0 + tx];
    __syncthreads();
#pragma unroll
    for (int j = 0; j < 32; j += 8)
        dst[(size_t)(d0 + ty + j) * 1024 + j0 + tx] = t[tx][ty + j];
}

// ---------------------------------------------------------------------------
// GEMM: C[M,N] = A[M,1024] @ Bt[N,1024]^T, bf16 MFMA, m97-style async staging.
// 128x128 tile, BK=32, 4 waves 2x2, each 64x64 via 4x4 16x16x32 MFMAs.
// MODE 0: +bias, scale cols<2048, split-write bf16 q/k/v(out2=scratch).
// MODE 1: +bias +residual(xn bf16), fp32 out.
// ---------------------------------------------------------------------------
template <int MODE>
__global__ __launch_bounds__(256) void gemm_bt(
    const ushort* __restrict__ A, const ushort* __restrict__ Bt,
    const float* __restrict__ bias, ushort* __restrict__ out0,
    ushort* __restrict__ out1, ushort* __restrict__ out2,
    const ushort* __restrict__ resid, float* __restrict__ outf) {
    const int K = 1024;
    __shared__ __align__(16) ushort As[128 * 32];
    __shared__ __align__(16) ushort Bs[128 * 32];

    int tid = threadIdx.x;
    int lane = tid & 63, w = tid >> 6;
    int l15 = lane & 15, q4 = lane >> 4;
    int wr = (w >> 1) * 64, wc = (w & 1) * 64;
    int rowBase = blockIdx.y * 128, colBase = blockIdx.x * 128;

    f32x4 acc[4][4];
    f32x4 zero = {0.f, 0.f, 0.f, 0.f};
#pragma unroll
    for (int mi = 0; mi < 4; mi++)
#pragma unroll
        for (int ni = 0; ni < 4; ni++) acc[mi][ni] = zero;

    for (int kt = 0; kt < K / 32; kt++) {
        __syncthreads();
#pragma unroll
        for (int i = 0; i < 2; i++) {
            int linear = w * 128 + i * 64 + lane;       // 16B chunk id, 0..511
            int r = linear >> 2, c8 = (linear & 3) * 8;
            gload_lds16(&A[(size_t)(rowBase + r) * K + kt * 32 + c8], &As[linear * 8]);
            gload_lds16(&Bt[(size_t)(colBase + r) * K + kt * 32 + c8], &Bs[linear * 8]);
        }
        __syncthreads();

        short8 aF[4], bF[4];
#pragma unroll
        for (int mi = 0; mi < 4; mi++)
            aF[mi] = *(const short8*)&As[(wr + mi * 16 + l15) * 32 + q4 * 8];
#pragma unroll
        for (int ni = 0; ni < 4; ni++)
            bF[ni] = *(const short8*)&Bs[(wc + ni * 16 + l15) * 32 + q4 * 8];
#pragma unroll
        for (int mi = 0; mi < 4; mi++)
#pragma unroll
            for (int ni = 0; ni < 4; ni++)
                acc[mi][ni] = __builtin_amdgcn_mfma_f32_16x16x32_bf16(
                    aF[mi], bF[ni], acc[mi][ni], 0, 0, 0);
    }

    // C layout: col = lane&15, row = (lane>>4)*4 + r  [m89/m91]
#pragma unroll
    for (int mi = 0; mi < 4; mi++)
#pragma unroll
        for (int ni = 0; ni < 4; ni++) {
            f32x4 a = acc[mi][ni];
            int col = colBase + wc + ni * 16 + l15;
            float bv = bias[col];
#pragma unroll
            for (int r = 0; r < 4; r++) {
                int row = rowBase + wr + mi * 16 + q4 * 4 + r;
                float val = a[r] + bv;
                if (MODE == 0) {
                    if (col < 2048) val *= QK_SCALE;
                    int bsel = col >> 10, cc = col & 1023;
                    ushort* dst = (bsel == 0) ? out0 : ((bsel == 1) ? out1 : out2);
                    dst[(size_t)row * 1024 + cc] = f2bf(val);
                } else {
                    val += bf2f(resid[(size_t)row * 1024 + col]);
                    outf[(size_t)row * 1024 + col] = val;
                }
            }
        }
}

// ---------------------------------------------------------------------------
// Attention v3.  One block = (head g, 128 q-rows); 4 waves, each 32 q.
// kt loop over 16 tiles of 64 keys.  No-max softmax (logits small, verified).
//  - Q fragments in registers (no LDS)
//  - Ks [64 key][128 d] staged via global_load_lds with XOR-16 chunk swizzle
//  - Vt [128 d][64 key] (stride 72) staged from precomputed global V^T
//  - Ps [128 q][64 key] (stride 72), produced/consumed within each wave
// ---------------------------------------------------------------------------
__global__ __launch_bounds__(256) void attn_kernel(
    const ushort* __restrict__ qb, const ushort* __restrict__ kb,
    const ushort* __restrict__ vt, ushort* __restrict__ ob) {
    int g = blockIdx.x >> 3;      // head 0..63
    int qblk = blockIdx.x & 7;    // 128-row q block
    const ushort* Qh = qb + (size_t)g * 131072;
    const ushort* Kh = kb + (size_t)g * 131072;
    const ushort* Vh = vt + (size_t)g * 131072;  // [128 d][1024 key]

    __shared__ __align__(16) ushort Ks[64 * 128];   // chunk-swizzled
    __shared__ __align__(16) ushort Vt[128 * 72];
    __shared__ __align__(16) ushort Ps[128 * 72];

    int tid = threadIdx.x, lane = tid & 63, w = tid >> 6;
    int l15 = lane & 15, q4 = lane >> 4;
    int q0 = qblk * 128 + w * 32;

    // Q fragments: A[m=l15][k = ks*32 + q4*8 + j], contiguous 16B in global
    short8 qf[2][4];
#pragma unroll
    for (int mi = 0; mi < 2; mi++)
#pragma unroll
        for (int ks = 0; ks < 4; ks++)
            qf[mi][ks] = *(const short8*)&Qh[(size_t)(q0 + mi * 16 + l15) * 128 + ks * 32 + q4 * 8];

    f32x4 zero = {0.f, 0.f, 0.f, 0.f};
    f32x4 o[2][8];
#pragma unroll
    for (int mi = 0; mi < 2; mi++)
#pragma unroll
        for (int ni = 0; ni < 8; ni++) o[mi][ni] = zero;
    float lsum[2][4] = {{0.f, 0.f, 0.f, 0.f}, {0.f, 0.f, 0.f, 0.f}};

    for (int kt = 0; kt < 16; kt++) {
        __syncthreads();
        // Ks: 1024 chunks of 16B; phys chunk p in row r holds logical l = p^(r&15)
#pragma unroll
        for (int i = 0; i < 4; i++) {
            int linear = i * 256 + w * 64 + lane;
            int r = linear >> 4, p = linear & 15;
            int l = p ^ (r & 15);
            gload_lds16(&Kh[(size_t)(kt * 64 + r) * 128 + l * 8], &Ks[linear * 8]);
        }
        // Vt: [d][key], padded stride 72, coalesced 16B both sides
#pragma unroll
        for (int i = 0; i < 4; i++) {
            int t = tid + i * 256;
            int d = t >> 3, c = (t & 7) * 8;
            *(uint4*)&Vt[d * 72 + c] = *(const uint4*)&Vh[(size_t)d * 1024 + kt * 64 + c];
        }
        __syncthreads();

        // S = Q K^T : 32q x 64key per wave
        f32x4 sacc[2][4];
#pragma unroll
        for (int mi = 0; mi < 2; mi++)
#pragma unroll
            for (int ni = 0; ni < 4; ni++) sacc[mi][ni] = zero;
#pragma unroll
        for (int ks = 0; ks < 4; ks++) {
            short8 bF[4];
#pragma unroll
            for (int ni = 0; ni < 4; ni++) {
                int r = ni * 16 + l15;
                int p = (ks * 4 + q4) ^ (r & 15);
                bF[ni] = *(const short8*)&Ks[r * 128 + p * 8];
            }
#pragma unroll
            for (int mi = 0; mi < 2; mi++)
#pragma unroll
                for (int ni = 0; ni < 4; ni++)
                    sacc[mi][ni] = __builtin_amdgcn_mfma_f32_16x16x32_bf16(
                        qf[mi][ks], bF[ni], sacc[mi][ni], 0, 0, 0);
        }

        // P = exp(S), write Ps, accumulate row sums
#pragma unroll
        for (int mi = 0; mi < 2; mi++) {
            float part[4] = {0.f, 0.f, 0.f, 0.f};
#pragma unroll
            for (int ni = 0; ni < 4; ni++)
#pragma unroll
                for (int r = 0; r < 4; r++) {
                    float pv = __expf(sacc[mi][ni][r]);
                    part[r] += pv;
                    Ps[(w * 32 + mi * 16 + q4 * 4 + r) * 72 + ni * 16 + l15] = f2bf(pv);
                }
#pragma unroll
            for (int r = 0; r < 4; r++) {
#pragma unroll
                for (int m = 1; m < 16; m <<= 1) part[r] += __shfl_xor(part[r], m, 16);
                lsum[mi][r] += part[r];
            }
        }

        // O += P V  (Ps rows are wave-private: no barrier needed)
#pragma unroll
        for (int ks2 = 0; ks2 < 2; ks2++) {
            short8 aF[2];
#pragma unroll
            for (int mi = 0; mi < 2; mi++)
                aF[mi] = *(const short8*)&Ps[(w * 32 + mi * 16 + l15) * 72 + ks2 * 32 + q4 * 8];
#pragma unroll
            for (int ni = 0; ni < 8; ni++) {
                short8 bF = *(const short8*)&Vt[(ni * 16 + l15) * 72 + ks2 * 32 + q4 * 8];
#pragma unroll
                for (int mi = 0; mi < 2; mi++)
                    o[mi][ni] = __builtin_amdgcn_mfma_f32_16x16x32_bf16(
                        aF[mi], bF, o[mi][ni], 0, 0, 0);
            }
        }
    }

    float inv[2][4];
#pragma unroll
    for (int mi = 0; mi < 2; mi++)
#pragma unroll
        for (int r = 0; r < 4; r++) inv[mi][r] = 1.0f / lsum[mi][r];
#pragma unroll
    for (int mi = 0; mi < 2; mi++)
#pragma unroll
        for (int ni = 0; ni < 8; ni++)
#pragma unroll
            for (int r = 0; r < 4; r++) {
                int qrow = q0 + mi * 16 + q4 * 4 + r;
                ob[(size_t)g * 131072 + (size_t)qrow * 128 + ni * 16 + l15] =
                    f2bf(o[mi][ni][r] * inv[mi][r]);
            }
}

// ---------------------------------------------------------------------------
extern "C" void kernel_launch(void* const* d_in, const int* in_sizes, int n_in,
                              void* d_out, int out_size, void* d_ws, size_t ws_size,
                              hipStream_t stream) {
    const float* x     = (const float*)d_in[0];
    const float* ln_g  = (const float*)d_in[1];
    const float* ln_b  = (const float*)d_in[2];
    const float* w_qkv = (const float*)d_in[3];
    const float* b_qkv = (const float*)d_in[4];
    const float* w_out = (const float*)d_in[5];
    const float* b_out = (const float*)d_in[6];
    float* out = (float*)d_out;

    const size_t MC = 8192ull * 1024ull;  // 8.39M elems
    ushort* xn    = (ushort*)d_ws;
    ushort* wqkvT = xn + MC;
    ushort* woutT = wqkvT + 3072ull * 1024ull;
    ushort* qbuf  = woutT + 1024ull * 1024ull;
    ushort* kbuf  = qbuf + MC;
    ushort* vtbuf = kbuf + MC;        // V^T [64][128][1024]
    ushort* attnb = vtbuf + MC;       // scratch for raw V, then attn output
    // total: 46.14M ushorts = 92.3 MB (same as passing round-2 layout)

    ln_kernel<<<8192, 256, 0, stream>>>(x, ln_g, ln_b, xn);
    transpose_kernel<<<dim3(96, 32), 256, 0, stream>>>(w_qkv, wqkvT, 1024, 3072);
    transpose_kernel<<<dim3(32, 32), 256, 0, stream>>>(w_out, woutT, 1024, 1024);
    // q,k -> qbuf,kbuf ; v -> attnb (scratch)
    gemm_bt<0><<<dim3(24, 64), 256, 0, stream>>>(xn, wqkvT, b_qkv, qbuf, kbuf, attnb, nullptr, nullptr);
    transpose_head<<<dim3(4, 32, 64), 256, 0, stream>>>(attnb, vtbuf);
    attn_kernel<<<512, 256, 0, stream>>>(qbuf, kbuf, vtbuf, attnb);
    gemm_bt<1><<<dim3(8, 64), 256, 0, stream>>>(attnb, woutT, b_out, nullptr, nullptr, nullptr, xn, out);
}

// Round 4
// 284.685 us; speedup vs baseline: 1.1063x; 1.0759x over previous
//
#include <hip/hip_runtime.h>
#include <hip/hip_bf16.h>

// ---------------------------------------------------------------------------
// AttentionBlock: B=8, L=1024, C=1024, H=8, ch=128.
// fp32 I/O, bf16 MFMA internal.  Head split is a free flat reinterpret.
// ---------------------------------------------------------------------------

typedef __attribute__((ext_vector_type(8))) short short8;
typedef __attribute__((ext_vector_type(4))) float f32x4;

#define QK_SCALE 0.29730177875068026f  // 128^-0.25

__device__ __forceinline__ float bf2f(ushort u) {
    union { float f; unsigned int i; } c; c.i = ((unsigned int)u) << 16; return c.f;
}
__device__ __forceinline__ ushort f2bf(float f) {
    union { float f; unsigned int i; } c; c.f = f;
    unsigned int x = c.i;
    return (ushort)((x + 0x7FFFu + ((x >> 16) & 1u)) >> 16);  // RNE
}

// async 16B global->LDS (m97; LDS dest must be wave-uniform base + lane*16)
__device__ __forceinline__ void gload_lds16(const ushort* g, ushort* l) {
    __builtin_amdgcn_global_load_lds(
        (const __attribute__((address_space(1))) unsigned int*)g,
        (__attribute__((address_space(3))) unsigned int*)l, 16, 0, 0);
}

// ---------------------------------------------------------------------------
// LayerNorm: one block per row of 1024.  fp32 in -> bf16 out.
// ---------------------------------------------------------------------------
__global__ __launch_bounds__(256) void ln_kernel(
    const float* __restrict__ x, const float* __restrict__ g,
    const float* __restrict__ b, ushort* __restrict__ xn) {
    int row = blockIdx.x;
    int tid = threadIdx.x;
    const float* xr = x + (size_t)row * 1024;
    float4 v4 = *(const float4*)(xr + tid * 4);
    float v[4] = {v4.x, v4.y, v4.z, v4.w};
    float s1 = 0.f, s2 = 0.f;
#pragma unroll
    for (int j = 0; j < 4; j++) { s1 += v[j]; s2 += v[j] * v[j]; }
#pragma unroll
    for (int m = 32; m >= 1; m >>= 1) { s1 += __shfl_xor(s1, m); s2 += __shfl_xor(s2, m); }
    __shared__ float r1[4], r2[4];
    int lane = tid & 63, w = tid >> 6;
    if (lane == 0) { r1[w] = s1; r2[w] = s2; }
    __syncthreads();
    s1 = r1[0] + r1[1] + r1[2] + r1[3];
    s2 = r2[0] + r2[1] + r2[2] + r2[3];
    float mu = s1 * (1.0f / 1024.0f);
    float var = s2 * (1.0f / 1024.0f) - mu * mu;
    float rs = rsqrtf(var + 1e-5f);
    int c0 = tid * 4;
    float4 gg = *(const float4*)(g + c0);
    float4 bb = *(const float4*)(b + c0);
    float gA[4] = {gg.x, gg.y, gg.z, gg.w};
    float bA[4] = {bb.x, bb.y, bb.z, bb.w};
    ushort o[4];
#pragma unroll
    for (int j = 0; j < 4; j++) o[j] = f2bf((v[j] - mu) * rs * gA[j] + bA[j]);
    uint2 pk;
    pk.x = (uint)o[0] | ((uint)o[1] << 16);
    pk.y = (uint)o[2] | ((uint)o[3] << 16);
    *(uint2*)(xn + (size_t)row * 1024 + c0) = pk;
}

// ---------------------------------------------------------------------------
// Weight transpose + fp32->bf16: in[R][Cc] fp32 -> out[Cc][R] bf16
// ---------------------------------------------------------------------------
__global__ __launch_bounds__(256) void transpose_kernel(
    const float* __restrict__ in, ushort* __restrict__ out, int R, int Cc) {
    __shared__ ushort t[32][33];
    int bx = blockIdx.x * 32, by = blockIdx.y * 32;
    int tx = threadIdx.x & 31, ty = threadIdx.x >> 5;
#pragma unroll
    for (int j = 0; j < 32; j += 8)
        t[ty + j][tx] = f2bf(in[(size_t)(by + ty + j) * Cc + bx + tx]);
    __syncthreads();
#pragma unroll
    for (int j = 0; j < 32; j += 8)
        out[(size_t)(bx + ty + j) * R + by + tx] = t[tx][ty + j];
}

// ---------------------------------------------------------------------------
// Per-head bf16 transpose: in [64][1024][128] -> out [64][128][1024]
// ---------------------------------------------------------------------------
__global__ __launch_bounds__(256) void transpose_head(
    const ushort* __restrict__ in, ushort* __restrict__ out) {
    __shared__ ushort t[32][33];
    int h = blockIdx.z;
    int j0 = blockIdx.y * 32;  // seq pos
    int d0 = blockIdx.x * 32;  // head dim
    int tx = threadIdx.x & 31, ty = threadIdx.x >> 5;
    const ushort* src = in + (size_t)h * 131072;
    ushort* dst = out + (size_t)h * 131072;
#pragma unroll
    for (int j = 0; j < 32; j += 8)
        t[ty + j][tx] = src[(size_t)(j0 + ty + j) * 128 + d0 + tx];
    __syncthreads();
#pragma unroll
    for (int j = 0; j < 32; j += 8)
        dst[(size_t)(d0 + ty + j) * 1024 + j0 + tx] = t[tx][ty + j];
}

// ---------------------------------------------------------------------------
// QKV GEMM: C[M,3072] = A[M,1024] @ Bt[3072,1024]^T, 128x128 tile, BK=32.
// +bias, scale cols<2048, split-write bf16 q/k/v(out2=v scratch).
// ---------------------------------------------------------------------------
__global__ __launch_bounds__(256) void gemm_qkv(
    const ushort* __restrict__ A, const ushort* __restrict__ Bt,
    const float* __restrict__ bias, ushort* __restrict__ out0,
    ushort* __restrict__ out1, ushort* __restrict__ out2) {
    const int K = 1024;
    __shared__ __align__(16) ushort As[128 * 32];
    __shared__ __align__(16) ushort Bs[128 * 32];

    int tid = threadIdx.x;
    int lane = tid & 63, w = tid >> 6;
    int l15 = lane & 15, q4 = lane >> 4;
    int wr = (w >> 1) * 64, wc = (w & 1) * 64;
    int rowBase = blockIdx.y * 128, colBase = blockIdx.x * 128;

    f32x4 acc[4][4];
    f32x4 zero = {0.f, 0.f, 0.f, 0.f};
#pragma unroll
    for (int mi = 0; mi < 4; mi++)
#pragma unroll
        for (int ni = 0; ni < 4; ni++) acc[mi][ni] = zero;

    for (int kt = 0; kt < K / 32; kt++) {
        __syncthreads();
#pragma unroll
        for (int i = 0; i < 2; i++) {
            int linear = w * 128 + i * 64 + lane;  // 16B chunk id, 0..511
            int r = linear >> 2, c8 = (linear & 3) * 8;
            gload_lds16(&A[(size_t)(rowBase + r) * K + kt * 32 + c8], &As[linear * 8]);
            gload_lds16(&Bt[(size_t)(colBase + r) * K + kt * 32 + c8], &Bs[linear * 8]);
        }
        __syncthreads();

        short8 aF[4], bF[4];
#pragma unroll
        for (int mi = 0; mi < 4; mi++)
            aF[mi] = *(const short8*)&As[(wr + mi * 16 + l15) * 32 + q4 * 8];
#pragma unroll
        for (int ni = 0; ni < 4; ni++)
            bF[ni] = *(const short8*)&Bs[(wc + ni * 16 + l15) * 32 + q4 * 8];
#pragma unroll
        for (int mi = 0; mi < 4; mi++)
#pragma unroll
            for (int ni = 0; ni < 4; ni++)
                acc[mi][ni] = __builtin_amdgcn_mfma_f32_16x16x32_bf16(
                    aF[mi], bF[ni], acc[mi][ni], 0, 0, 0);
    }

    // C layout: col = lane&15, row = (lane>>4)*4 + r  [m89/m91]
#pragma unroll
    for (int mi = 0; mi < 4; mi++)
#pragma unroll
        for (int ni = 0; ni < 4; ni++) {
            f32x4 a = acc[mi][ni];
            int col = colBase + wc + ni * 16 + l15;
            float bv = bias[col];
#pragma unroll
            for (int r = 0; r < 4; r++) {
                int row = rowBase + wr + mi * 16 + q4 * 4 + r;
                float val = a[r] + bv;
                if (col < 2048) val *= QK_SCALE;
                int bsel = col >> 10, cc = col & 1023;
                ushort* dst = (bsel == 0) ? out0 : ((bsel == 1) ? out1 : out2);
                dst[(size_t)row * 1024 + cc] = f2bf(val);
            }
        }
}

// ---------------------------------------------------------------------------
// Out-proj GEMM: outf[M,1024] = A[M,1024] @ Bt[1024,1024]^T + bias + resid.
// 64x128 tile, BK=32, grid (8,128)=1024 blocks, 12 KB LDS -> high occupancy.
// 4 waves 2x2, each 32x64 (acc 2x4).
// ---------------------------------------------------------------------------
__global__ __launch_bounds__(256, 4) void gemm_out(
    const ushort* __restrict__ A, const ushort* __restrict__ Bt,
    const float* __restrict__ bias, const ushort* __restrict__ resid,
    float* __restrict__ outf) {
    const int K = 1024;
    __shared__ __align__(16) ushort As[64 * 32];    // 256 chunks
    __shared__ __align__(16) ushort Bs[128 * 32];   // 512 chunks

    int tid = threadIdx.x;
    int lane = tid & 63, w = tid >> 6;
    int l15 = lane & 15, q4 = lane >> 4;
    int wr = (w >> 1) * 32, wc = (w & 1) * 64;
    int rowBase = blockIdx.y * 64, colBase = blockIdx.x * 128;

    f32x4 acc[2][4];
    f32x4 zero = {0.f, 0.f, 0.f, 0.f};
#pragma unroll
    for (int mi = 0; mi < 2; mi++)
#pragma unroll
        for (int ni = 0; ni < 4; ni++) acc[mi][ni] = zero;

    for (int kt = 0; kt < K / 32; kt++) {
        __syncthreads();
#pragma unroll
        for (int i = 0; i < 3; i++) {
            int id = i * 256 + w * 64 + lane;  // 0..767, wave-contiguous
            if (id < 256) {
                int r = id >> 2, c8 = (id & 3) * 8;
                gload_lds16(&A[(size_t)(rowBase + r) * K + kt * 32 + c8], &As[id * 8]);
            } else {
                int idb = id - 256;
                int r = idb >> 2, c8 = (idb & 3) * 8;
                gload_lds16(&Bt[(size_t)(colBase + r) * K + kt * 32 + c8], &Bs[idb * 8]);
            }
        }
        __syncthreads();

        short8 aF[2], bF[4];
#pragma unroll
        for (int mi = 0; mi < 2; mi++)
            aF[mi] = *(const short8*)&As[(wr + mi * 16 + l15) * 32 + q4 * 8];
#pragma unroll
        for (int ni = 0; ni < 4; ni++)
            bF[ni] = *(const short8*)&Bs[(wc + ni * 16 + l15) * 32 + q4 * 8];
#pragma unroll
        for (int mi = 0; mi < 2; mi++)
#pragma unroll
            for (int ni = 0; ni < 4; ni++)
                acc[mi][ni] = __builtin_amdgcn_mfma_f32_16x16x32_bf16(
                    aF[mi], bF[ni], acc[mi][ni], 0, 0, 0);
    }

#pragma unroll
    for (int mi = 0; mi < 2; mi++)
#pragma unroll
        for (int ni = 0; ni < 4; ni++) {
            f32x4 a = acc[mi][ni];
            int col = colBase + wc + ni * 16 + l15;
            float bv = bias[col];
#pragma unroll
            for (int r = 0; r < 4; r++) {
                int row = rowBase + wr + mi * 16 + q4 * 4 + r;
                float val = a[r] + bv + bf2f(resid[(size_t)row * 1024 + col]);
                outf[(size_t)row * 1024 + col] = val;
            }
        }
}

// ---------------------------------------------------------------------------
// Attention v4.  One block = (head g, 64 q-rows); 4 waves x 16q.
// Grid 1024 blocks; LDS exactly 40 KB -> 4 blocks/CU; VGPR <=128 -> 16 wv/CU.
//  - Q fragments in registers
//  - Ks [64 key][128 d], XOR-16 chunk swizzle, global_load_lds staged
//  - Vt [128 d][64 key], XOR-8 chunk swizzle (phys c = c ^ (d&7))
//  - Ps [64 q][64 key],  XOR-8 chunk swizzle (phys c = c ^ (q&7))
//  - per-lane softmax partials; single cross-lane reduce at end
// ---------------------------------------------------------------------------
__global__ __launch_bounds__(256, 4) void attn_kernel(
    const ushort* __restrict__ qb, const ushort* __restrict__ kb,
    const ushort* __restrict__ vt, ushort* __restrict__ ob) {
    int g = blockIdx.x >> 4;       // head 0..63
    int qblk = blockIdx.x & 15;    // 64-row q block
    const ushort* Qh = qb + (size_t)g * 131072;
    const ushort* Kh = kb + (size_t)g * 131072;
    const ushort* Vh = vt + (size_t)g * 131072;  // [128 d][1024 key]

    __shared__ __align__(16) ushort Ks[64 * 128];  // 16 KB
    __shared__ __align__(16) ushort Vt[128 * 64];  // 16 KB
    __shared__ __align__(16) ushort Ps[64 * 64];   //  8 KB

    int tid = threadIdx.x, lane = tid & 63, w = tid >> 6;
    int l15 = lane & 15, q4 = lane >> 4;
    int q0 = qblk * 64;

    // Q A-fragments: A[m=l15][k = ks*32 + q4*8 + j]
    short8 qf[4];
#pragma unroll
    for (int ks = 0; ks < 4; ks++)
        qf[ks] = *(const short8*)&Qh[(size_t)(q0 + w * 16 + l15) * 128 + ks * 32 + q4 * 8];

    f32x4 zero = {0.f, 0.f, 0.f, 0.f};
    f32x4 o[8];
#pragma unroll
    for (int ni = 0; ni < 8; ni++) o[ni] = zero;
    float plsum[4] = {0.f, 0.f, 0.f, 0.f};

    for (int kt = 0; kt < 16; kt++) {
        __syncthreads();
        // Ks: phys chunk p in key-row r holds logical chunk l = p ^ (r&15)
#pragma unroll
        for (int i = 0; i < 4; i++) {
            int linear = i * 256 + w * 64 + lane;
            int r = linear >> 4, p = linear & 15;
            int l = p ^ (r & 15);
            gload_lds16(&Kh[(size_t)(kt * 64 + r) * 128 + l * 8], &Ks[linear * 8]);
        }
        // Vt: phys chunk = c ^ (d&7)
#pragma unroll
        for (int i = 0; i < 4; i++) {
            int id = i * 256 + tid;
            int d = id >> 3, c = id & 7;
            int pc = c ^ (d & 7);
            *(uint4*)&Vt[d * 64 + pc * 8] =
                *(const uint4*)&Vh[(size_t)d * 1024 + kt * 64 + c * 8];
        }
        __syncthreads();

        // S = Q K^T : 16q x 64key per wave
        f32x4 sacc[4];
#pragma unroll
        for (int ni = 0; ni < 4; ni++) sacc[ni] = zero;
#pragma unroll
        for (int ks = 0; ks < 4; ks++) {
#pragma unroll
            for (int ni = 0; ni < 4; ni++) {
                int r = ni * 16 + l15;
                int p = (ks * 4 + q4) ^ (r & 15);
                short8 bF = *(const short8*)&Ks[r * 128 + p * 8];
                sacc[ni] = __builtin_amdgcn_mfma_f32_16x16x32_bf16(
                    qf[ks], bF, sacc[ni], 0, 0, 0);
            }
        }

        // P = exp(S) -> Ps (swizzled); accumulate per-lane partial row sums
#pragma unroll
        for (int ni = 0; ni < 4; ni++) {
#pragma unroll
            for (int r = 0; r < 4; r++) {
                float pv = __expf(sacc[ni][r]);
                plsum[r] += pv;
                int qloc = w * 16 + q4 * 4 + r;
                int key = ni * 16 + l15;
                int pc = (key >> 3) ^ (qloc & 7);
                Ps[qloc * 64 + pc * 8 + (key & 7)] = f2bf(pv);
            }
        }

        // O += P V  (wave-private Ps rows; same-wave RAW handled by waitcnt)
#pragma unroll
        for (int ks2 = 0; ks2 < 2; ks2++) {
            int c = ks2 * 4 + q4;
            short8 aF = *(const short8*)&Ps[(w * 16 + l15) * 64 + (c ^ (l15 & 7)) * 8];
#pragma unroll
            for (int ni = 0; ni < 8; ni++) {
                int d = ni * 16 + l15;
                short8 bF = *(const short8*)&Vt[d * 64 + (c ^ (d & 7)) * 8];
                o[ni] = __builtin_amdgcn_mfma_f32_16x16x32_bf16(aF, bF, o[ni], 0, 0, 0);
            }
        }
    }

    // row sums: reduce per-lane partials over the 16 l15-lanes
#pragma unroll
    for (int r = 0; r < 4; r++) {
#pragma unroll
        for (int m = 1; m < 16; m <<= 1) plsum[r] += __shfl_xor(plsum[r], m, 16);
    }
    float inv[4];
#pragma unroll
    for (int r = 0; r < 4; r++) inv[r] = 1.0f / plsum[r];
#pragma unroll
    for (int ni = 0; ni < 8; ni++)
#pragma unroll
        for (int r = 0; r < 4; r++) {
            int qrow = q0 + w * 16 + q4 * 4 + r;
            ob[(size_t)g * 131072 + (size_t)qrow * 128 + ni * 16 + l15] =
                f2bf(o[ni][r] * inv[r]);
        }
}

// ---------------------------------------------------------------------------
extern "C" void kernel_launch(void* const* d_in, const int* in_sizes, int n_in,
                              void* d_out, int out_size, void* d_ws, size_t ws_size,
                              hipStream_t stream) {
    const float* x     = (const float*)d_in[0];
    const float* ln_g  = (const float*)d_in[1];
    const float* ln_b  = (const float*)d_in[2];
    const float* w_qkv = (const float*)d_in[3];
    const float* b_qkv = (const float*)d_in[4];
    const float* w_out = (const float*)d_in[5];
    const float* b_out = (const float*)d_in[6];
    float* out = (float*)d_out;

    const size_t MC = 8192ull * 1024ull;  // 8.39M elems
    ushort* xn    = (ushort*)d_ws;
    ushort* wqkvT = xn + MC;
    ushort* woutT = wqkvT + 3072ull * 1024ull;
    ushort* qbuf  = woutT + 1024ull * 1024ull;
    ushort* kbuf  = qbuf + MC;
    ushort* vtbuf = kbuf + MC;        // V^T [64][128][1024]
    ushort* attnb = vtbuf + MC;       // scratch for raw V, then attn output
    // total: 46.14M ushorts = 92.3 MB (same as passing rounds 2-3)

    ln_kernel<<<8192, 256, 0, stream>>>(x, ln_g, ln_b, xn);
    transpose_kernel<<<dim3(96, 32), 256, 0, stream>>>(w_qkv, wqkvT, 1024, 3072);
    transpose_kernel<<<dim3(32, 32), 256, 0, stream>>>(w_out, woutT, 1024, 1024);
    // q,k -> qbuf,kbuf ; v -> attnb (scratch)
    gemm_qkv<<<dim3(24, 64), 256, 0, stream>>>(xn, wqkvT, b_qkv, qbuf, kbuf, attnb);
    transpose_head<<<dim3(4, 32, 64), 256, 0, stream>>>(attnb, vtbuf);
    attn_kernel<<<1024, 256, 0, stream>>>(qbuf, kbuf, vtbuf, attnb);
    gemm_out<<<dim3(8, 128), 256, 0, stream>>>(attnb, woutT, b_out, xn, out);
}

// Round 5
// 268.392 us; speedup vs baseline: 1.1735x; 1.0607x over previous
//
#include <hip/hip_runtime.h>
#include <hip/hip_bf16.h>

// ---------------------------------------------------------------------------
// AttentionBlock: B=8, L=1024, C=1024, H=8, ch=128.
// fp32 I/O, bf16 MFMA internal.  Head split is a free flat reinterpret.
// ---------------------------------------------------------------------------

typedef __attribute__((ext_vector_type(8))) short short8;
typedef __attribute__((ext_vector_type(4))) float f32x4;

#define QK_SCALE 0.29730177875068026f  // 128^-0.25

__device__ __forceinline__ float bf2f(ushort u) {
    union { float f; unsigned int i; } c; c.i = ((unsigned int)u) << 16; return c.f;
}
__device__ __forceinline__ ushort f2bf(float f) {
    union { float f; unsigned int i; } c; c.f = f;
    unsigned int x = c.i;
    return (ushort)((x + 0x7FFFu + ((x >> 16) & 1u)) >> 16);  // RNE
}

// async 16B global->LDS (m97; LDS dest must be wave-uniform base + lane*16)
__device__ __forceinline__ void gload_lds16(const ushort* g, ushort* l) {
    __builtin_amdgcn_global_load_lds(
        (const __attribute__((address_space(1))) unsigned int*)g,
        (__attribute__((address_space(3))) unsigned int*)l, 16, 0, 0);
}

// ---------------------------------------------------------------------------
// LayerNorm: one block per row of 1024.  fp32 in -> bf16 out.
// ---------------------------------------------------------------------------
__global__ __launch_bounds__(256) void ln_kernel(
    const float* __restrict__ x, const float* __restrict__ g,
    const float* __restrict__ b, ushort* __restrict__ xn) {
    int row = blockIdx.x;
    int tid = threadIdx.x;
    const float* xr = x + (size_t)row * 1024;
    float4 v4 = *(const float4*)(xr + tid * 4);
    float v[4] = {v4.x, v4.y, v4.z, v4.w};
    float s1 = 0.f, s2 = 0.f;
#pragma unroll
    for (int j = 0; j < 4; j++) { s1 += v[j]; s2 += v[j] * v[j]; }
#pragma unroll
    for (int m = 32; m >= 1; m >>= 1) { s1 += __shfl_xor(s1, m); s2 += __shfl_xor(s2, m); }
    __shared__ float r1[4], r2[4];
    int lane = tid & 63, w = tid >> 6;
    if (lane == 0) { r1[w] = s1; r2[w] = s2; }
    __syncthreads();
    s1 = r1[0] + r1[1] + r1[2] + r1[3];
    s2 = r2[0] + r2[1] + r2[2] + r2[3];
    float mu = s1 * (1.0f / 1024.0f);
    float var = s2 * (1.0f / 1024.0f) - mu * mu;
    float rs = rsqrtf(var + 1e-5f);
    int c0 = tid * 4;
    float4 gg = *(const float4*)(g + c0);
    float4 bb = *(const float4*)(b + c0);
    float gA[4] = {gg.x, gg.y, gg.z, gg.w};
    float bA[4] = {bb.x, bb.y, bb.z, bb.w};
    ushort o[4];
#pragma unroll
    for (int j = 0; j < 4; j++) o[j] = f2bf((v[j] - mu) * rs * gA[j] + bA[j]);
    uint2 pk;
    pk.x = (uint)o[0] | ((uint)o[1] << 16);
    pk.y = (uint)o[2] | ((uint)o[3] << 16);
    *(uint2*)(xn + (size_t)row * 1024 + c0) = pk;
}

// ---------------------------------------------------------------------------
// Weight transpose + fp32->bf16: in[R][Cc] fp32 -> out[Cc][R] bf16
// ---------------------------------------------------------------------------
__global__ __launch_bounds__(256) void transpose_kernel(
    const float* __restrict__ in, ushort* __restrict__ out, int R, int Cc) {
    __shared__ ushort t[32][33];
    int bx = blockIdx.x * 32, by = blockIdx.y * 32;
    int tx = threadIdx.x & 31, ty = threadIdx.x >> 5;
#pragma unroll
    for (int j = 0; j < 32; j += 8)
        t[ty + j][tx] = f2bf(in[(size_t)(by + ty + j) * Cc + bx + tx]);
    __syncthreads();
#pragma unroll
    for (int j = 0; j < 32; j += 8)
        out[(size_t)(bx + ty + j) * R + by + tx] = t[tx][ty + j];
}

// ---------------------------------------------------------------------------
// Per-head bf16 transpose: in [64][1024][128] -> out [64][128][1024]
// ---------------------------------------------------------------------------
__global__ __launch_bounds__(256) void transpose_head(
    const ushort* __restrict__ in, ushort* __restrict__ out) {
    __shared__ ushort t[32][33];
    int h = blockIdx.z;
    int j0 = blockIdx.y * 32;  // seq pos
    int d0 = blockIdx.x * 32;  // head dim
    int tx = threadIdx.x & 31, ty = threadIdx.x >> 5;
    const ushort* src = in + (size_t)h * 131072;
    ushort* dst = out + (size_t)h * 131072;
#pragma unroll
    for (int j = 0; j < 32; j += 8)
        t[ty + j][tx] = src[(size_t)(j0 + ty + j) * 128 + d0 + tx];
    __syncthreads();
#pragma unroll
    for (int j = 0; j < 32; j += 8)
        dst[(size_t)(d0 + ty + j) * 1024 + j0 + tx] = t[tx][ty + j];
}

// ---------------------------------------------------------------------------
// QKV GEMM: C[M,3072] = A[M,1024] @ Bt[3072,1024]^T, 128x128 tile, BK=64,
// XOR-8 chunk swizzle (phys 16B-chunk p = c ^ (r&7); row=128B wraps banks).
// 32 MFMA per barrier pair.  +bias, scale cols<2048, split-write q/k/v.
// ---------------------------------------------------------------------------
__global__ __launch_bounds__(256) void gemm_qkv(
    const ushort* __restrict__ A, const ushort* __restrict__ Bt,
    const float* __restrict__ bias, ushort* __restrict__ out0,
    ushort* __restrict__ out1, ushort* __restrict__ out2) {
    const int K = 1024;
    __shared__ __align__(16) ushort As[128 * 64];  // 16 KB
    __shared__ __align__(16) ushort Bs[128 * 64];  // 16 KB

    int tid = threadIdx.x;
    int lane = tid & 63, w = tid >> 6;
    int l15 = lane & 15, q4 = lane >> 4;
    int wr = (w >> 1) * 64, wc = (w & 1) * 64;
    int rowBase = blockIdx.y * 128, colBase = blockIdx.x * 128;

    f32x4 acc[4][4];
    f32x4 zero = {0.f, 0.f, 0.f, 0.f};
#pragma unroll
    for (int mi = 0; mi < 4; mi++)
#pragma unroll
        for (int ni = 0; ni < 4; ni++) acc[mi][ni] = zero;

    for (int kt = 0; kt < 16; kt++) {
        __syncthreads();
#pragma unroll
        for (int i = 0; i < 4; i++) {
            int linear = i * 256 + w * 64 + lane;  // 16B chunk id, 0..1023
            int r = linear >> 3, p = linear & 7;
            int l = p ^ (r & 7);
            gload_lds16(&A[(size_t)(rowBase + r) * K + kt * 64 + l * 8], &As[linear * 8]);
            gload_lds16(&Bt[(size_t)(colBase + r) * K + kt * 64 + l * 8], &Bs[linear * 8]);
        }
        __syncthreads();

#pragma unroll
        for (int kk = 0; kk < 2; kk++) {
            short8 aF[4], bF[4];
#pragma unroll
            for (int mi = 0; mi < 4; mi++) {
                int r = wr + mi * 16 + l15;
                aF[mi] = *(const short8*)&As[r * 64 + ((kk * 4 + q4) ^ (r & 7)) * 8];
            }
#pragma unroll
            for (int ni = 0; ni < 4; ni++) {
                int r = wc + ni * 16 + l15;
                bF[ni] = *(const short8*)&Bs[r * 64 + ((kk * 4 + q4) ^ (r & 7)) * 8];
            }
#pragma unroll
            for (int mi = 0; mi < 4; mi++)
#pragma unroll
                for (int ni = 0; ni < 4; ni++)
                    acc[mi][ni] = __builtin_amdgcn_mfma_f32_16x16x32_bf16(
                        aF[mi], bF[ni], acc[mi][ni], 0, 0, 0);
        }
    }

    // C layout: col = lane&15, row = (lane>>4)*4 + r  [m89/m91]
#pragma unroll
    for (int mi = 0; mi < 4; mi++)
#pragma unroll
        for (int ni = 0; ni < 4; ni++) {
            f32x4 a = acc[mi][ni];
            int col = colBase + wc + ni * 16 + l15;
            float bv = bias[col];
#pragma unroll
            for (int r = 0; r < 4; r++) {
                int row = rowBase + wr + mi * 16 + q4 * 4 + r;
                float val = a[r] + bv;
                if (col < 2048) val *= QK_SCALE;
                int bsel = col >> 10, cc = col & 1023;
                ushort* dst = (bsel == 0) ? out0 : ((bsel == 1) ? out1 : out2);
                dst[(size_t)row * 1024 + cc] = f2bf(val);
            }
        }
}

// ---------------------------------------------------------------------------
// Out-proj GEMM: outf[M,1024] = A[M,1024] @ Bt[1024,1024]^T + bias + resid.
// 64x128 tile, BK=64, XOR-8 swizzle, grid (8,128)=1024 blocks, 24 KB LDS.
// ---------------------------------------------------------------------------
__global__ __launch_bounds__(256, 4) void gemm_out(
    const ushort* __restrict__ A, const ushort* __restrict__ Bt,
    const float* __restrict__ bias, const ushort* __restrict__ resid,
    float* __restrict__ outf) {
    const int K = 1024;
    __shared__ __align__(16) ushort As[64 * 64];    //  8 KB, 512 chunks
    __shared__ __align__(16) ushort Bs[128 * 64];   // 16 KB, 1024 chunks

    int tid = threadIdx.x;
    int lane = tid & 63, w = tid >> 6;
    int l15 = lane & 15, q4 = lane >> 4;
    int wr = (w >> 1) * 32, wc = (w & 1) * 64;
    int rowBase = blockIdx.y * 64, colBase = blockIdx.x * 128;

    f32x4 acc[2][4];
    f32x4 zero = {0.f, 0.f, 0.f, 0.f};
#pragma unroll
    for (int mi = 0; mi < 2; mi++)
#pragma unroll
        for (int ni = 0; ni < 4; ni++) acc[mi][ni] = zero;

    for (int kt = 0; kt < 16; kt++) {
        __syncthreads();
#pragma unroll
        for (int i = 0; i < 6; i++) {
            int id = i * 256 + w * 64 + lane;  // 0..1535, wave-contiguous runs
            if (id < 512) {
                int r = id >> 3, p = id & 7;
                int l = p ^ (r & 7);
                gload_lds16(&A[(size_t)(rowBase + r) * K + kt * 64 + l * 8], &As[id * 8]);
            } else {
                int idb = id - 512;
                int r = idb >> 3, p = idb & 7;
                int l = p ^ (r & 7);
                gload_lds16(&Bt[(size_t)(colBase + r) * K + kt * 64 + l * 8], &Bs[idb * 8]);
            }
        }
        __syncthreads();

#pragma unroll
        for (int kk = 0; kk < 2; kk++) {
            short8 aF[2], bF[4];
#pragma unroll
            for (int mi = 0; mi < 2; mi++) {
                int r = wr + mi * 16 + l15;
                aF[mi] = *(const short8*)&As[r * 64 + ((kk * 4 + q4) ^ (r & 7)) * 8];
            }
#pragma unroll
            for (int ni = 0; ni < 4; ni++) {
                int r = wc + ni * 16 + l15;
                bF[ni] = *(const short8*)&Bs[r * 64 + ((kk * 4 + q4) ^ (r & 7)) * 8];
            }
#pragma unroll
            for (int mi = 0; mi < 2; mi++)
#pragma unroll
                for (int ni = 0; ni < 4; ni++)
                    acc[mi][ni] = __builtin_amdgcn_mfma_f32_16x16x32_bf16(
                        aF[mi], bF[ni], acc[mi][ni], 0, 0, 0);
        }
    }

#pragma unroll
    for (int mi = 0; mi < 2; mi++)
#pragma unroll
        for (int ni = 0; ni < 4; ni++) {
            f32x4 a = acc[mi][ni];
            int col = colBase + wc + ni * 16 + l15;
            float bv = bias[col];
#pragma unroll
            for (int r = 0; r < 4; r++) {
                int row = rowBase + wr + mi * 16 + q4 * 4 + r;
                float val = a[r] + bv + bf2f(resid[(size_t)row * 1024 + col]);
                outf[(size_t)row * 1024 + col] = val;
            }
        }
}

// ---------------------------------------------------------------------------
// Attention v4 (unchanged from round 4).  One block = (head g, 64 q-rows).
// ---------------------------------------------------------------------------
__global__ __launch_bounds__(256, 4) void attn_kernel(
    const ushort* __restrict__ qb, const ushort* __restrict__ kb,
    const ushort* __restrict__ vt, ushort* __restrict__ ob) {
    int g = blockIdx.x >> 4;       // head 0..63
    int qblk = blockIdx.x & 15;    // 64-row q block
    const ushort* Qh = qb + (size_t)g * 131072;
    const ushort* Kh = kb + (size_t)g * 131072;
    const ushort* Vh = vt + (size_t)g * 131072;  // [128 d][1024 key]

    __shared__ __align__(16) ushort Ks[64 * 128];  // 16 KB
    __shared__ __align__(16) ushort Vt[128 * 64];  // 16 KB
    __shared__ __align__(16) ushort Ps[64 * 64];   //  8 KB

    int tid = threadIdx.x, lane = tid & 63, w = tid >> 6;
    int l15 = lane & 15, q4 = lane >> 4;
    int q0 = qblk * 64;

    // Q A-fragments: A[m=l15][k = ks*32 + q4*8 + j]
    short8 qf[4];
#pragma unroll
    for (int ks = 0; ks < 4; ks++)
        qf[ks] = *(const short8*)&Qh[(size_t)(q0 + w * 16 + l15) * 128 + ks * 32 + q4 * 8];

    f32x4 zero = {0.f, 0.f, 0.f, 0.f};
    f32x4 o[8];
#pragma unroll
    for (int ni = 0; ni < 8; ni++) o[ni] = zero;
    float plsum[4] = {0.f, 0.f, 0.f, 0.f};

    for (int kt = 0; kt < 16; kt++) {
        __syncthreads();
        // Ks: phys chunk p in key-row r holds logical chunk l = p ^ (r&15)
#pragma unroll
        for (int i = 0; i < 4; i++) {
            int linear = i * 256 + w * 64 + lane;
            int r = linear >> 4, p = linear & 15;
            int l = p ^ (r & 15);
            gload_lds16(&Kh[(size_t)(kt * 64 + r) * 128 + l * 8], &Ks[linear * 8]);
        }
        // Vt: phys chunk = c ^ (d&7)
#pragma unroll
        for (int i = 0; i < 4; i++) {
            int id = i * 256 + tid;
            int d = id >> 3, c = id & 7;
            int pc = c ^ (d & 7);
            *(uint4*)&Vt[d * 64 + pc * 8] =
                *(const uint4*)&Vh[(size_t)d * 1024 + kt * 64 + c * 8];
        }
        __syncthreads();

        // S = Q K^T : 16q x 64key per wave
        f32x4 sacc[4];
#pragma unroll
        for (int ni = 0; ni < 4; ni++) sacc[ni] = zero;
#pragma unroll
        for (int ks = 0; ks < 4; ks++) {
#pragma unroll
            for (int ni = 0; ni < 4; ni++) {
                int r = ni * 16 + l15;
                int p = (ks * 4 + q4) ^ (r & 15);
                short8 bF = *(const short8*)&Ks[r * 128 + p * 8];
                sacc[ni] = __builtin_amdgcn_mfma_f32_16x16x32_bf16(
                    qf[ks], bF, sacc[ni], 0, 0, 0);
            }
        }

        // P = exp(S) -> Ps (swizzled); accumulate per-lane partial row sums
#pragma unroll
        for (int ni = 0; ni < 4; ni++) {
#pragma unroll
            for (int r = 0; r < 4; r++) {
                float pv = __expf(sacc[ni][r]);
                plsum[r] += pv;
                int qloc = w * 16 + q4 * 4 + r;
                int key = ni * 16 + l15;
                int pc = (key >> 3) ^ (qloc & 7);
                Ps[qloc * 64 + pc * 8 + (key & 7)] = f2bf(pv);
            }
        }

        // O += P V  (wave-private Ps rows; same-wave RAW handled by waitcnt)
#pragma unroll
        for (int ks2 = 0; ks2 < 2; ks2++) {
            int c = ks2 * 4 + q4;
            short8 aF = *(const short8*)&Ps[(w * 16 + l15) * 64 + (c ^ (l15 & 7)) * 8];
#pragma unroll
            for (int ni = 0; ni < 8; ni++) {
                int d = ni * 16 + l15;
                short8 bF = *(const short8*)&Vt[d * 64 + (c ^ (d & 7)) * 8];
                o[ni] = __builtin_amdgcn_mfma_f32_16x16x32_bf16(aF, bF, o[ni], 0, 0, 0);
            }
        }
    }

    // row sums: reduce per-lane partials over the 16 l15-lanes
#pragma unroll
    for (int r = 0; r < 4; r++) {
#pragma unroll
        for (int m = 1; m < 16; m <<= 1) plsum[r] += __shfl_xor(plsum[r], m, 16);
    }
    float inv[4];
#pragma unroll
    for (int r = 0; r < 4; r++) inv[r] = 1.0f / plsum[r];
#pragma unroll
    for (int ni = 0; ni < 8; ni++)
#pragma unroll
        for (int r = 0; r < 4; r++) {
            int qrow = q0 + w * 16 + q4 * 4 + r;
            ob[(size_t)g * 131072 + (size_t)qrow * 128 + ni * 16 + l15] =
                f2bf(o[ni][r] * inv[r]);
        }
}

// ---------------------------------------------------------------------------
extern "C" void kernel_launch(void* const* d_in, const int* in_sizes, int n_in,
                              void* d_out, int out_size, void* d_ws, size_t ws_size,
                              hipStream_t stream) {
    const float* x     = (const float*)d_in[0];
    const float* ln_g  = (const float*)d_in[1];
    const float* ln_b  = (const float*)d_in[2];
    const float* w_qkv = (const float*)d_in[3];
    const float* b_qkv = (const float*)d_in[4];
    const float* w_out = (const float*)d_in[5];
    const float* b_out = (const float*)d_in[6];
    float* out = (float*)d_out;

    const size_t MC = 8192ull * 1024ull;  // 8.39M elems
    ushort* xn    = (ushort*)d_ws;
    ushort* wqkvT = xn + MC;
    ushort* woutT = wqkvT + 3072ull * 1024ull;
    ushort* qbuf  = woutT + 1024ull * 1024ull;
    ushort* kbuf  = qbuf + MC;
    ushort* vtbuf = kbuf + MC;        // V^T [64][128][1024]
    ushort* attnb = vtbuf + MC;       // scratch for raw V, then attn output
    // total: 46.14M ushorts = 92.3 MB (same as passing rounds 2-4)

    ln_kernel<<<8192, 256, 0, stream>>>(x, ln_g, ln_b, xn);
    transpose_kernel<<<dim3(96, 32), 256, 0, stream>>>(w_qkv, wqkvT, 1024, 3072);
    transpose_kernel<<<dim3(32, 32), 256, 0, stream>>>(w_out, woutT, 1024, 1024);
    // q,k -> qbuf,kbuf ; v -> attnb (scratch)
    gemm_qkv<<<dim3(24, 64), 256, 0, stream>>>(xn, wqkvT, b_qkv, qbuf, kbuf, attnb);
    transpose_head<<<dim3(4, 32, 64), 256, 0, stream>>>(attnb, vtbuf);
    attn_kernel<<<1024, 256, 0, stream>>>(qbuf, kbuf, vtbuf, attnb);
    gemm_out<<<dim3(8, 128), 256, 0, stream>>>(attnb, woutT, b_out, xn, out);
}

// Round 7
// 264.932 us; speedup vs baseline: 1.1888x; 1.0131x over previous
//
#include <hip/hip_runtime.h>
#include <hip/hip_bf16.h>

// ---------------------------------------------------------------------------
// AttentionBlock: B=8, L=1024, C=1024, H=8, ch=128.
// fp32 I/O, bf16 MFMA internal.  Head split is a free flat reinterpret.
// ---------------------------------------------------------------------------

typedef __attribute__((ext_vector_type(8))) short short8;
typedef __attribute__((ext_vector_type(4))) float f32x4;

#define QK_SCALE 0.29730177875068026f  // 128^-0.25

__device__ __forceinline__ float bf2f(ushort u) {
    union { float f; unsigned int i; } c; c.i = ((unsigned int)u) << 16; return c.f;
}
__device__ __forceinline__ ushort f2bf(float f) {
    union { float f; unsigned int i; } c; c.f = f;
    unsigned int x = c.i;
    return (ushort)((x + 0x7FFFu + ((x >> 16) & 1u)) >> 16);  // RNE
}

// async 16B global->LDS (m97; LDS dest must be wave-uniform base + lane*16)
__device__ __forceinline__ void gload_lds16(const ushort* g, ushort* l) {
    __builtin_amdgcn_global_load_lds(
        (const __attribute__((address_space(1))) unsigned int*)g,
        (__attribute__((address_space(3))) unsigned int*)l, 16, 0, 0);
}

// ---------------------------------------------------------------------------
// Prep kernel: fuses LayerNorm (blocks 0..8191) + w_qkv transpose
// (8192..11263) + w_out transpose (11264..12287).  All fp32 in -> bf16 out.
// ---------------------------------------------------------------------------
__global__ __launch_bounds__(256) void prep_kernel(
    const float* __restrict__ x, const float* __restrict__ g,
    const float* __restrict__ b, ushort* __restrict__ xn,
    const float* __restrict__ w_qkv, ushort* __restrict__ wqkvT,
    const float* __restrict__ w_out, ushort* __restrict__ woutT) {
    __shared__ float r1[4], r2[4];
    __shared__ ushort t[32][33];
    int bid = blockIdx.x;
    int tid = threadIdx.x;
    if (bid < 8192) {
        // ---- LayerNorm row ----
        int row = bid;
        const float* xr = x + (size_t)row * 1024;
        float4 v4 = *(const float4*)(xr + tid * 4);
        float v[4] = {v4.x, v4.y, v4.z, v4.w};
        float s1 = 0.f, s2 = 0.f;
#pragma unroll
        for (int j = 0; j < 4; j++) { s1 += v[j]; s2 += v[j] * v[j]; }
#pragma unroll
        for (int m = 32; m >= 1; m >>= 1) { s1 += __shfl_xor(s1, m); s2 += __shfl_xor(s2, m); }
        int lane = tid & 63, w = tid >> 6;
        if (lane == 0) { r1[w] = s1; r2[w] = s2; }
        __syncthreads();
        s1 = r1[0] + r1[1] + r1[2] + r1[3];
        s2 = r2[0] + r2[1] + r2[2] + r2[3];
        float mu = s1 * (1.0f / 1024.0f);
        float var = s2 * (1.0f / 1024.0f) - mu * mu;
        float rs = rsqrtf(var + 1e-5f);
        int c0 = tid * 4;
        float4 gg = *(const float4*)(g + c0);
        float4 bb = *(const float4*)(b + c0);
        float gA[4] = {gg.x, gg.y, gg.z, gg.w};
        float bA[4] = {bb.x, bb.y, bb.z, bb.w};
        ushort o[4];
#pragma unroll
        for (int j = 0; j < 4; j++) o[j] = f2bf((v[j] - mu) * rs * gA[j] + bA[j]);
        uint2 pk;
        pk.x = (uint)o[0] | ((uint)o[1] << 16);
        pk.y = (uint)o[2] | ((uint)o[3] << 16);
        *(uint2*)(xn + (size_t)row * 1024 + c0) = pk;
    } else {
        // ---- weight transpose tile ----
        const float* in; ushort* out; int R, Cc, bx, by;
        if (bid < 11264) {
            int tt = bid - 8192;
            in = w_qkv; out = wqkvT; R = 1024; Cc = 3072;
            bx = (tt % 96) * 32; by = (tt / 96) * 32;
        } else {
            int tt = bid - 11264;
            in = w_out; out = woutT; R = 1024; Cc = 1024;
            bx = (tt % 32) * 32; by = (tt / 32) * 32;
        }
        int tx = tid & 31, ty = tid >> 5;
#pragma unroll
        for (int j = 0; j < 32; j += 8)
            t[ty + j][tx] = f2bf(in[(size_t)(by + ty + j) * Cc + bx + tx]);
        __syncthreads();
#pragma unroll
        for (int j = 0; j < 32; j += 8)
            out[(size_t)(bx + ty + j) * R + by + tx] = t[tx][ty + j];
    }
}

// ---------------------------------------------------------------------------
// Per-head bf16 transpose: in [64][1024][128] -> out [64][128][1024]
// ---------------------------------------------------------------------------
__global__ __launch_bounds__(256) void transpose_head(
    const ushort* __restrict__ in, ushort* __restrict__ out) {
    __shared__ ushort t[32][33];
    int h = blockIdx.z;
    int j0 = blockIdx.y * 32;  // seq pos
    int d0 = blockIdx.x * 32;  // head dim
    int tx = threadIdx.x & 31, ty = threadIdx.x >> 5;
    const ushort* src = in + (size_t)h * 131072;
    ushort* dst = out + (size_t)h * 131072;
#pragma unroll
    for (int j = 0; j < 32; j += 8)
        t[ty + j][tx] = src[(size_t)(j0 + ty + j) * 128 + d0 + tx];
    __syncthreads();
#pragma unroll
    for (int j = 0; j < 32; j += 8)
        dst[(size_t)(d0 + ty + j) * 1024 + j0 + tx] = t[tx][ty + j];
}

// ---------------------------------------------------------------------------
// QKV GEMM: C[M,3072] = A[M,1024] @ Bt[3072,1024]^T, 128x128 tile, BK=64,
// XOR-8 chunk swizzle (conflict-free, verified R5: SQ_LDS_BANK_CONFLICT=0).
// Staging via persistent incremented pointers (VALU cut).
// ---------------------------------------------------------------------------
__global__ __launch_bounds__(256) void gemm_qkv(
    const ushort* __restrict__ A, const ushort* __restrict__ Bt,
    const float* __restrict__ bias, ushort* __restrict__ out0,
    ushort* __restrict__ out1, ushort* __restrict__ out2) {
    const int K = 1024;
    __shared__ __align__(16) ushort As[128 * 64];  // 16 KB
    __shared__ __align__(16) ushort Bs[128 * 64];  // 16 KB

    int tid = threadIdx.x;
    int lane = tid & 63, w = tid >> 6;
    int l15 = lane & 15, q4 = lane >> 4;
    int wr = (w >> 1) * 64, wc = (w & 1) * 64;
    int rowBase = blockIdx.y * 128, colBase = blockIdx.x * 128;

    // persistent staging pointers (incremented by BK each kt)
    const ushort* aS[4]; const ushort* bS[4];
    ushort* aD[4]; ushort* bD[4];
#pragma unroll
    for (int i = 0; i < 4; i++) {
        int linear = i * 256 + w * 64 + lane;  // 16B chunk id, 0..1023
        int r = linear >> 3;
        int l = (linear & 7) ^ (r & 7);
        aS[i] = A + (size_t)(rowBase + r) * K + l * 8;
        bS[i] = Bt + (size_t)(colBase + r) * K + l * 8;
        aD[i] = &As[linear * 8];
        bD[i] = &Bs[linear * 8];
    }

    f32x4 acc[4][4];
    f32x4 zero = {0.f, 0.f, 0.f, 0.f};
#pragma unroll
    for (int mi = 0; mi < 4; mi++)
#pragma unroll
        for (int ni = 0; ni < 4; ni++) acc[mi][ni] = zero;

    for (int kt = 0; kt < 16; kt++) {
        __syncthreads();
#pragma unroll
        for (int i = 0; i < 4; i++) {
            gload_lds16(aS[i], aD[i]);
            gload_lds16(bS[i], bD[i]);
            aS[i] += 64; bS[i] += 64;
        }
        __syncthreads();

#pragma unroll
        for (int kk = 0; kk < 2; kk++) {
            short8 aF[4], bF[4];
#pragma unroll
            for (int mi = 0; mi < 4; mi++) {
                int r = wr + mi * 16 + l15;
                aF[mi] = *(const short8*)&As[r * 64 + ((kk * 4 + q4) ^ (r & 7)) * 8];
            }
#pragma unroll
            for (int ni = 0; ni < 4; ni++) {
                int r = wc + ni * 16 + l15;
                bF[ni] = *(const short8*)&Bs[r * 64 + ((kk * 4 + q4) ^ (r & 7)) * 8];
            }
#pragma unroll
            for (int mi = 0; mi < 4; mi++)
#pragma unroll
                for (int ni = 0; ni < 4; ni++)
                    acc[mi][ni] = __builtin_amdgcn_mfma_f32_16x16x32_bf16(
                        aF[mi], bF[ni], acc[mi][ni], 0, 0, 0);
        }
    }

    // C layout: col = lane&15, row = (lane>>4)*4 + r  [m89/m91]
    // ni-outer: dst/scale/cc uniform over (mi,r) -- a 16-col run never
    // crosses a 1024 boundary (runs are 16-aligned).
#pragma unroll
    for (int ni = 0; ni < 4; ni++) {
        int col = colBase + wc + ni * 16 + l15;
        float bv = bias[col];
        float sc = (col < 2048) ? QK_SCALE : 1.0f;
        int bsel = col >> 10, cc = col & 1023;
        ushort* dst = (bsel == 0) ? out0 : ((bsel == 1) ? out1 : out2);
#pragma unroll
        for (int mi = 0; mi < 4; mi++) {
            f32x4 a = acc[mi][ni];
#pragma unroll
            for (int r = 0; r < 4; r++) {
                int row = rowBase + wr + mi * 16 + q4 * 4 + r;
                dst[(size_t)row * 1024 + cc] = f2bf((a[r] + bv) * sc);
            }
        }
    }
}

// ---------------------------------------------------------------------------
// Out-proj GEMM: outf[M,1024] = A[M,1024] @ Bt[1024,1024]^T + bias + resid.
// 64x128 tile, BK=64, XOR-8 swizzle, grid (8,128)=1024 blocks, 24 KB LDS.
// ---------------------------------------------------------------------------
__global__ __launch_bounds__(256, 4) void gemm_out(
    const ushort* __restrict__ A, const ushort* __restrict__ Bt,
    const float* __restrict__ bias, const ushort* __restrict__ resid,
    float* __restrict__ outf) {
    const int K = 1024;
    __shared__ __align__(16) ushort As[64 * 64];    //  8 KB, 512 chunks
    __shared__ __align__(16) ushort Bs[128 * 64];   // 16 KB, 1024 chunks

    int tid = threadIdx.x;
    int lane = tid & 63, w = tid >> 6;
    int l15 = lane & 15, q4 = lane >> 4;
    int wr = (w >> 1) * 32, wc = (w & 1) * 64;
    int rowBase = blockIdx.y * 64, colBase = blockIdx.x * 128;

    const ushort* src[6]; ushort* dstp[6];
#pragma unroll
    for (int i = 0; i < 6; i++) {
        int id = i * 256 + w * 64 + lane;  // 0..1535
        if (id < 512) {
            int r = id >> 3, l = (id & 7) ^ ((id >> 3) & 7);
            src[i] = A + (size_t)(rowBase + r) * K + l * 8;
            dstp[i] = &As[id * 8];
        } else {
            int idb = id - 512;
            int r = idb >> 3, l = (idb & 7) ^ ((idb >> 3) & 7);
            src[i] = Bt + (size_t)(colBase + r) * K + l * 8;
            dstp[i] = &Bs[idb * 8];
        }
    }

    f32x4 acc[2][4];
    f32x4 zero = {0.f, 0.f, 0.f, 0.f};
#pragma unroll
    for (int mi = 0; mi < 2; mi++)
#pragma unroll
        for (int ni = 0; ni < 4; ni++) acc[mi][ni] = zero;

    for (int kt = 0; kt < 16; kt++) {
        __syncthreads();
#pragma unroll
        for (int i = 0; i < 6; i++) {
            gload_lds16(src[i], dstp[i]);
            src[i] += 64;
        }
        __syncthreads();

#pragma unroll
        for (int kk = 0; kk < 2; kk++) {
            short8 aF[2], bF[4];
#pragma unroll
            for (int mi = 0; mi < 2; mi++) {
                int r = wr + mi * 16 + l15;
                aF[mi] = *(const short8*)&As[r * 64 + ((kk * 4 + q4) ^ (r & 7)) * 8];
            }
#pragma unroll
            for (int ni = 0; ni < 4; ni++) {
                int r = wc + ni * 16 + l15;
                bF[ni] = *(const short8*)&Bs[r * 64 + ((kk * 4 + q4) ^ (r & 7)) * 8];
            }
#pragma unroll
            for (int mi = 0; mi < 2; mi++)
#pragma unroll
                for (int ni = 0; ni < 4; ni++)
                    acc[mi][ni] = __builtin_amdgcn_mfma_f32_16x16x32_bf16(
                        aF[mi], bF[ni], acc[mi][ni], 0, 0, 0);
        }
    }

#pragma unroll
    for (int ni = 0; ni < 4; ni++) {
        int col = colBase + wc + ni * 16 + l15;
        float bv = bias[col];
#pragma unroll
        for (int mi = 0; mi < 2; mi++) {
            f32x4 a = acc[mi][ni];
#pragma unroll
            for (int r = 0; r < 4; r++) {
                int row = rowBase + wr + mi * 16 + q4 * 4 + r;
                outf[(size_t)row * 1024 + col] =
                    a[r] + bv + bf2f(resid[(size_t)row * 1024 + col]);
            }
        }
    }
}

// ---------------------------------------------------------------------------
// Attention v5 (fixed).  One block = (head g, 64 q-rows); 2 waves x 32 q.
// R6 bug: Vt staging loop ran i<4 with 128 threads -> only half of Vt staged
// (d rows 64..127 = uninitialized LDS -> NaN).  Fixed to i<8.
//  - Q fragments in registers (2 q-tiles x 4 k-frags)
//  - Ks [64 key][128 d], XOR-16 chunk swizzle, global_load_lds staged
//  - Vt [128 d][64 key], XOR-8 chunk swizzle (phys c = c ^ (d&7))
//  - Ps [64 q][64 key],  XOR-8 chunk swizzle (phys c = c ^ (q&7)), wave-private
// ---------------------------------------------------------------------------
__global__ __launch_bounds__(128, 2) void attn_kernel(
    const ushort* __restrict__ qb, const ushort* __restrict__ kb,
    const ushort* __restrict__ vt, ushort* __restrict__ ob) {
    int g = blockIdx.x >> 4;       // head 0..63
    int qblk = blockIdx.x & 15;    // 64-row q block
    const ushort* Qh = qb + (size_t)g * 131072;
    const ushort* Kh = kb + (size_t)g * 131072;
    const ushort* Vh = vt + (size_t)g * 131072;  // [128 d][1024 key]

    __shared__ __align__(16) ushort Ks[64 * 128];  // 16 KB
    __shared__ __align__(16) ushort Vt[128 * 64];  // 16 KB
    __shared__ __align__(16) ushort Ps[64 * 64];   //  8 KB

    int tid = threadIdx.x, lane = tid & 63, w = tid >> 6;  // w in {0,1}
    int l15 = lane & 15, q4 = lane >> 4;
    int q0 = qblk * 64;

    // Q A-fragments: A[m=l15][k = ks*32 + q4*8 + j], 2 q-tiles per wave
    short8 qf[2][4];
#pragma unroll
    for (int mi = 0; mi < 2; mi++)
#pragma unroll
        for (int ks = 0; ks < 4; ks++)
            qf[mi][ks] = *(const short8*)
                &Qh[(size_t)(q0 + w * 32 + mi * 16 + l15) * 128 + ks * 32 + q4 * 8];

    f32x4 zero = {0.f, 0.f, 0.f, 0.f};
    f32x4 o[2][8];
#pragma unroll
    for (int mi = 0; mi < 2; mi++)
#pragma unroll
        for (int ni = 0; ni < 8; ni++) o[mi][ni] = zero;
    float plsum[2][4] = {{0.f, 0.f, 0.f, 0.f}, {0.f, 0.f, 0.f, 0.f}};

    for (int kt = 0; kt < 16; kt++) {
        __syncthreads();
        // Ks: phys chunk p in key-row r holds logical chunk l = p ^ (r&15)
#pragma unroll
        for (int i = 0; i < 8; i++) {
            int linear = i * 128 + w * 64 + lane;
            int r = linear >> 4, p = linear & 15;
            int l = p ^ (r & 15);
            gload_lds16(&Kh[(size_t)(kt * 64 + r) * 128 + l * 8], &Ks[linear * 8]);
        }
        // Vt: phys chunk = c ^ (d&7)   (8 iters x 128 thr = 1024 chunks)
#pragma unroll
        for (int i = 0; i < 8; i++) {
            int id = i * 128 + tid;
            int d = id >> 3, c = id & 7;
            int pc = c ^ (d & 7);
            *(uint4*)&Vt[d * 64 + pc * 8] =
                *(const uint4*)&Vh[(size_t)d * 1024 + kt * 64 + c * 8];
        }
        __syncthreads();

        // S = Q K^T : 32q x 64key per wave (bF reused across 2 q-tiles)
        f32x4 sacc[2][4];
#pragma unroll
        for (int mi = 0; mi < 2; mi++)
#pragma unroll
            for (int ni = 0; ni < 4; ni++) sacc[mi][ni] = zero;
#pragma unroll
        for (int ks = 0; ks < 4; ks++) {
            short8 bF[4];
#pragma unroll
            for (int ni = 0; ni < 4; ni++) {
                int r = ni * 16 + l15;
                int p = (ks * 4 + q4) ^ (r & 15);
                bF[ni] = *(const short8*)&Ks[r * 128 + p * 8];
            }
#pragma unroll
            for (int mi = 0; mi < 2; mi++)
#pragma unroll
                for (int ni = 0; ni < 4; ni++)
                    sacc[mi][ni] = __builtin_amdgcn_mfma_f32_16x16x32_bf16(
                        qf[mi][ks], bF[ni], sacc[mi][ni], 0, 0, 0);
        }

        // P = exp(S) -> Ps (swizzled); per-lane partial row sums
#pragma unroll
        for (int mi = 0; mi < 2; mi++)
#pragma unroll
            for (int ni = 0; ni < 4; ni++)
#pragma unroll
                for (int r = 0; r < 4; r++) {
                    float pv = __expf(sacc[mi][ni][r]);
                    plsum[mi][r] += pv;
                    int qloc = w * 32 + mi * 16 + q4 * 4 + r;
                    int key = ni * 16 + l15;
                    int pc = (key >> 3) ^ (qloc & 7);
                    Ps[qloc * 64 + pc * 8 + (key & 7)] = f2bf(pv);
                }

        // O += P V  (wave-private Ps rows; same-wave RAW via waitcnt)
#pragma unroll
        for (int kb2 = 0; kb2 < 2; kb2++) {
            int c = kb2 * 4 + q4;
            short8 aF[2];
#pragma unroll
            for (int mi = 0; mi < 2; mi++) {
                int row = w * 32 + mi * 16 + l15;  // row&7 == l15&7
                aF[mi] = *(const short8*)&Ps[row * 64 + (c ^ (l15 & 7)) * 8];
            }
#pragma unroll
            for (int ni = 0; ni < 8; ni++) {
                int d = ni * 16 + l15;
                short8 bF = *(const short8*)&Vt[d * 64 + (c ^ (d & 7)) * 8];
#pragma unroll
                for (int mi = 0; mi < 2; mi++)
                    o[mi][ni] = __builtin_amdgcn_mfma_f32_16x16x32_bf16(
                        aF[mi], bF, o[mi][ni], 0, 0, 0);
            }
        }
    }

    // row sums: reduce per-lane partials over the 16 l15-lanes
#pragma unroll
    for (int mi = 0; mi < 2; mi++)
#pragma unroll
        for (int r = 0; r < 4; r++) {
#pragma unroll
            for (int m = 1; m < 16; m <<= 1)
                plsum[mi][r] += __shfl_xor(plsum[mi][r], m, 16);
        }
#pragma unroll
    for (int mi = 0; mi < 2; mi++) {
        float inv[4];
#pragma unroll
        for (int r = 0; r < 4; r++) inv[r] = 1.0f / plsum[mi][r];
#pragma unroll
        for (int ni = 0; ni < 8; ni++)
#pragma unroll
            for (int r = 0; r < 4; r++) {
                int qrow = q0 + w * 32 + mi * 16 + q4 * 4 + r;
                ob[(size_t)g * 131072 + (size_t)qrow * 128 + ni * 16 + l15] =
                    f2bf(o[mi][ni][r] * inv[r]);
            }
    }
}

// ---------------------------------------------------------------------------
extern "C" void kernel_launch(void* const* d_in, const int* in_sizes, int n_in,
                              void* d_out, int out_size, void* d_ws, size_t ws_size,
                              hipStream_t stream) {
    const float* x     = (const float*)d_in[0];
    const float* ln_g  = (const float*)d_in[1];
    const float* ln_b  = (const float*)d_in[2];
    const float* w_qkv = (const float*)d_in[3];
    const float* b_qkv = (const float*)d_in[4];
    const float* w_out = (const float*)d_in[5];
    const float* b_out = (const float*)d_in[6];
    float* out = (float*)d_out;

    const size_t MC = 8192ull * 1024ull;  // 8.39M elems
    ushort* xn    = (ushort*)d_ws;
    ushort* wqkvT = xn + MC;
    ushort* woutT = wqkvT + 3072ull * 1024ull;
    ushort* qbuf  = woutT + 1024ull * 1024ull;
    ushort* kbuf  = qbuf + MC;
    ushort* vtbuf = kbuf + MC;        // V^T [64][128][1024]
    ushort* attnb = vtbuf + MC;       // scratch for raw V, then attn output
    // total: 46.14M ushorts = 92.3 MB (same as passing rounds 2-5)

    prep_kernel<<<12288, 256, 0, stream>>>(x, ln_g, ln_b, xn, w_qkv, wqkvT, w_out, woutT);
    // q,k -> qbuf,kbuf ; v -> attnb (scratch)
    gemm_qkv<<<dim3(24, 64), 256, 0, stream>>>(xn, wqkvT, b_qkv, qbuf, kbuf, attnb);
    transpose_head<<<dim3(4, 32, 64), 256, 0, stream>>>(attnb, vtbuf);
    attn_kernel<<<1024, 128, 0, stream>>>(qbuf, kbuf, vtbuf, attnb);
    gemm_out<<<dim3(8, 128), 256, 0, stream>>>(attnb, woutT, b_out, xn, out);
}